// Round 3
// baseline (95.643 us; speedup 1.0000x reference)
//
#include <hip/hip_runtime.h>

// SpatialAttention2D MFMA v3: B=2, C=64, N=4096, 4 heads x d=16, fp32 io.
// vs v2: (a) LDS tiles stored fragment-ordered [chunk][lane] -> every frag
//        read is lane-linear ds_read_b64, zero bank conflicts;
//        (b) key-split KS=4 (no-max softmax partials are plain sums) ->
//        4096 waves = 4 waves/SIMD for latency hiding; reduce kernel combines;
//        (c) qkv_proj uses float4 LDS reads (broadcast) and 512 blocks.

#define NTOK 4096
#define HD   16
#define BH   8
#define KS   4                 // key splits
#define KT   256               // keys staged per LDS tile
#define CHUNKS (KT/16)         // 16
#define KEYS_BLK (NTOK/KS)     // 1024
#define NSTAGE (KEYS_BLK/KT)   // 4

typedef __attribute__((ext_vector_type(4))) short short4v;
typedef __attribute__((ext_vector_type(4))) float float4v;
typedef __attribute__((ext_vector_type(4))) ushort ushort4v;
typedef __attribute__((ext_vector_type(2))) unsigned uint2v;

__device__ __forceinline__ ushort f2bf(float f) {
  unsigned u = __builtin_bit_cast(unsigned, f);
  u += 0x7fffu + ((u >> 16) & 1u);          // round-to-nearest-even
  return (ushort)(u >> 16);
}

__device__ __forceinline__ float fast_exp2(float x) {
#if __has_builtin(__builtin_amdgcn_exp2f)
  return __builtin_amdgcn_exp2f(x);
#else
  return exp2f(x);
#endif
}

// ws layout: bf16 region (ushort offsets), then fp32 region (float offsets)
#define QB_OFF 0
#define KB_OFF ((size_t)BH*NTOK*HD)
#define VT_OFF (2*(size_t)BH*NTOK*HD)
#define PACC_F ((size_t)3*BH*NTOK*HD/2)          // float offset = 786432
#define PL_F   (PACC_F + (size_t)BH*KS*HD*NTOK)  // + 2097152
// total floats = 3,014,656 (~12.1 MB)

// ---------------------------------------------------------------------------
// Kernel 1: QKV projection. 512 blocks x 192 threads (one out-channel each),
// 16 tokens per block. LDS reads are float4 broadcasts (conflict-free).
// q scaled by 0.25*log2(e); V written transposed.
// ---------------------------------------------------------------------------
__global__ __launch_bounds__(192) void qkv_proj(
    const float* __restrict__ x, const float* __restrict__ w,
    const float* __restrict__ bias, ushort* __restrict__ wsu) {
  const int TOK = 16;
  int blk = blockIdx.x;            // 2 * 4096/16 = 512
  int b   = blk >> 8;
  int n0  = (blk & 255) * TOK;
  int o   = threadIdx.x;           // 0..191

  __shared__ float4 xs4[64][TOK/4];   // 4 KB
  const float4* x4 = reinterpret_cast<const float4*>(x);
  for (int idx = threadIdx.x; idx < 64*(TOK/4); idx += 192) {
    int c = idx >> 2, t4 = idx & 3;
    xs4[c][t4] = x4[((size_t)b*64 + c)*(NTOK/4) + (n0 >> 2) + t4];
  }

  float wr[64];
  const float4* w4 = reinterpret_cast<const float4*>(w + o*64);
  #pragma unroll
  for (int i = 0; i < 16; ++i) {
    float4 tt = w4[i];
    wr[4*i+0]=tt.x; wr[4*i+1]=tt.y; wr[4*i+2]=tt.z; wr[4*i+3]=tt.w;
  }
  float bb = bias[o];

  int part = o >> 6;               // 0=q,1=k,2=v
  int oo   = o & 63;
  int h    = oo >> 4;
  int dd   = oo & 15;
  int bh   = b*4 + h;
  const float QSCALE = 0.25f * 1.44269504f;

  ushort* Qb = wsu + QB_OFF;
  ushort* Kb = wsu + KB_OFF;
  ushort* Vt = wsu + VT_OFF;

  __syncthreads();

  #pragma unroll
  for (int t4 = 0; t4 < TOK/4; ++t4) {
    float a[4] = {bb, bb, bb, bb};
    #pragma unroll
    for (int c = 0; c < 64; ++c) {
      float4 xv = xs4[c][t4];
      float wv = wr[c];
      a[0] = fmaf(xv.x, wv, a[0]);
      a[1] = fmaf(xv.y, wv, a[1]);
      a[2] = fmaf(xv.z, wv, a[2]);
      a[3] = fmaf(xv.w, wv, a[3]);
    }
    if (part == 0) {
      #pragma unroll
      for (int j = 0; j < 4; ++j)
        Qb[((size_t)bh*NTOK + n0 + t4*4 + j)*HD + dd] = f2bf(a[j]*QSCALE);
    } else if (part == 1) {
      #pragma unroll
      for (int j = 0; j < 4; ++j)
        Kb[((size_t)bh*NTOK + n0 + t4*4 + j)*HD + dd] = f2bf(a[j]);
    } else {
      ushort4v vv = { f2bf(a[0]), f2bf(a[1]), f2bf(a[2]), f2bf(a[3]) };
      *(ushort4v*)(Vt + ((size_t)bh*HD + dd)*NTOK + n0 + t4*4) = vv;
    }
  }
}

// ---------------------------------------------------------------------------
// Kernel 2: MFMA flash attention partials. Grid = 8 bh x 32 qblk x 4 ks = 1024
// blocks, 4 waves x 32 q-rows. LDS tiles fragment-ordered: [chunk][lane] ->
// frag reads are lane-linear b64 (conflict-free). Writes unnormalized acc + l.
// ---------------------------------------------------------------------------
__global__ __launch_bounds__(256, 4) void attn_mfma(
    const ushort* __restrict__ wsu, float* __restrict__ wsf) {
  const ushort* Qb = wsu + QB_OFF;
  const ushort* Kb = wsu + KB_OFF;
  const ushort* Vt = wsu + VT_OFF;
  float* pacc = wsf + PACC_F;
  float* pl   = wsf + PL_F;

  int blk  = blockIdx.x;
  int bh   = blk >> 7;
  int qblk = (blk >> 2) & 31;
  int ks   = blk & 3;
  int tid  = threadIdx.x;
  int wid  = tid >> 6;
  int lane = tid & 63;
  int lr   = lane & 15;
  int g4   = (lane >> 4) << 2;
  int qbase = qblk*128 + wid*32;

  __shared__ short4v Ksw[CHUNKS][64];   // 8 KB: frag for chunk c, lane l
  __shared__ short4v Vsw[CHUNKS][64];   // 8 KB

  const ushort* Kh = Kb + (size_t)bh*NTOK*HD;
  const ushort* Vh = Vt + (size_t)bh*HD*NTOK;
  const ushort* Qh = Qb + (size_t)bh*NTOK*HD;

  // Q fragments (B operand): lane l holds Q[q = l&15][d = g4..g4+3]
  short4v qf0 = *(const short4v*)(Qh + (size_t)(qbase      + lr)*HD + g4);
  short4v qf1 = *(const short4v*)(Qh + (size_t)(qbase + 16 + lr)*HD + g4);

  float4v acc0 = {0.f,0.f,0.f,0.f}, acc1 = {0.f,0.f,0.f,0.f};
  float l0 = 0.f, l1 = 0.f;

  // staging decomposition (stage-local), 2 K-loads + 2 V-loads per thread:
  // K load i: key kk = i>>1 (0..255), d half kh = (i&1)*8.
  //   dest slots: c = kk>>4, s0 = (kh>>2)*16 + (kk&15), s1 = s0+16.
  // V load i: row vr = i>>5 (d), cols vc..vc+7, vc = (i&31)*8.
  //   dest slots: c = vc>>4, s0 = ((vc&15)>>2)*16 + vr, s1 = s0+16.
  int ik0 = tid, ik1 = tid + 256;
  int kk0 = ik0 >> 1, kh0 = (ik0 & 1) * 8;
  int kk1 = ik1 >> 1, kh1 = (ik1 & 1) * 8;
  int kc0 = kk0 >> 4, ks0 = (kh0 >> 2)*16 + (kk0 & 15);
  int kc1 = kk1 >> 4, ks1s = (kh1 >> 2)*16 + (kk1 & 15);
  int vr0 = ik0 >> 5, vc0 = (ik0 & 31) * 8;
  int vr1 = ik1 >> 5, vc1 = (ik1 & 31) * 8;
  int vcc0 = vc0 >> 4, vs0 = ((vc0 & 15) >> 2)*16 + vr0;
  int vcc1 = vc1 >> 4, vs1 = ((vc1 & 15) >> 2)*16 + vr1;

  int kbase = ks * KEYS_BLK;

  // prologue: stage 0
  uint4 pk0 = *(const uint4*)(Kh + (size_t)(kbase + kk0)*HD + kh0);
  uint4 pk1 = *(const uint4*)(Kh + (size_t)(kbase + kk1)*HD + kh1);
  uint4 pv0 = *(const uint4*)(Vh + (size_t)vr0*NTOK + kbase + vc0);
  uint4 pv1 = *(const uint4*)(Vh + (size_t)vr1*NTOK + kbase + vc1);
  {
    uint2v a = {pk0.x, pk0.y}, bq = {pk0.z, pk0.w};
    *(uint2v*)&Ksw[kc0][ks0] = a;  *(uint2v*)&Ksw[kc0][ks0+16] = bq;
    uint2v c2 = {pk1.x, pk1.y}, d2 = {pk1.z, pk1.w};
    *(uint2v*)&Ksw[kc1][ks1s] = c2; *(uint2v*)&Ksw[kc1][ks1s+16] = d2;
    uint2v e2 = {pv0.x, pv0.y}, f2 = {pv0.z, pv0.w};
    *(uint2v*)&Vsw[vcc0][vs0] = e2; *(uint2v*)&Vsw[vcc0][vs0+16] = f2;
    uint2v g2 = {pv1.x, pv1.y}, h2 = {pv1.z, pv1.w};
    *(uint2v*)&Vsw[vcc1][vs1] = g2; *(uint2v*)&Vsw[vcc1][vs1+16] = h2;
  }
  __syncthreads();

  for (int s = 0; s < NSTAGE; ++s) {
    if (s + 1 < NSTAGE) {          // T14: issue next-stage loads early
      int k0n = kbase + (s + 1) * KT;
      pk0 = *(const uint4*)(Kh + (size_t)(k0n + kk0)*HD + kh0);
      pk1 = *(const uint4*)(Kh + (size_t)(k0n + kk1)*HD + kh1);
      pv0 = *(const uint4*)(Vh + (size_t)vr0*NTOK + k0n + vc0);
      pv1 = *(const uint4*)(Vh + (size_t)vr1*NTOK + k0n + vc1);
    }
    #pragma unroll
    for (int c = 0; c < CHUNKS; ++c) {
      short4v kf = Ksw[c][lane];   // K[key=c*16+lr][d=g4..g4+3]
      short4v vf = Vsw[c][lane];   // V^T[d=lr][key=c*16+g4..+3]
      float4v zero = {0.f,0.f,0.f,0.f};
      float4v s0 = __builtin_amdgcn_mfma_f32_16x16x16bf16_1k(kf, qf0, zero, 0, 0, 0);
      float4v s1 = __builtin_amdgcn_mfma_f32_16x16x16bf16_1k(kf, qf1, zero, 0, 0, 0);
      short4v pb0, pb1;
      #pragma unroll
      for (int r = 0; r < 4; ++r) {
        float p0 = fast_exp2(s0[r]); l0 += p0; pb0[r] = (short)f2bf(p0);
        float p1 = fast_exp2(s1[r]); l1 += p1; pb1[r] = (short)f2bf(p1);
      }
      acc0 = __builtin_amdgcn_mfma_f32_16x16x16bf16_1k(vf, pb0, acc0, 0, 0, 0);
      acc1 = __builtin_amdgcn_mfma_f32_16x16x16bf16_1k(vf, pb1, acc1, 0, 0, 0);
    }
    __syncthreads();
    if (s + 1 < NSTAGE) {
      uint2v a = {pk0.x, pk0.y}, bq = {pk0.z, pk0.w};
      *(uint2v*)&Ksw[kc0][ks0] = a;  *(uint2v*)&Ksw[kc0][ks0+16] = bq;
      uint2v c2 = {pk1.x, pk1.y}, d2 = {pk1.z, pk1.w};
      *(uint2v*)&Ksw[kc1][ks1s] = c2; *(uint2v*)&Ksw[kc1][ks1s+16] = d2;
      uint2v e2 = {pv0.x, pv0.y}, f2 = {pv0.z, pv0.w};
      *(uint2v*)&Vsw[vcc0][vs0] = e2; *(uint2v*)&Vsw[vcc0][vs0+16] = f2;
      uint2v g2 = {pv1.x, pv1.y}, h2 = {pv1.z, pv1.w};
      *(uint2v*)&Vsw[vcc1][vs1] = g2; *(uint2v*)&Vsw[vcc1][vs1+16] = h2;
      __syncthreads();
    }
  }

  // reduce lsum across the 4 lane-groups (same q at lanes l^16, l^32, l^48)
  l0 += __shfl_xor(l0, 16); l0 += __shfl_xor(l0, 32);
  l1 += __shfl_xor(l1, 16); l1 += __shfl_xor(l1, 32);

  // partials: pacc[bh][ks][d][n] unnormalized; pl[bh][ks][n]
  float* pb = pacc + ((size_t)(bh*KS + ks)*HD) * NTOK;
  #pragma unroll
  for (int r = 0; r < 4; ++r) {
    pb[(size_t)(g4 + r)*NTOK + qbase      + lr] = acc0[r];
    pb[(size_t)(g4 + r)*NTOK + qbase + 16 + lr] = acc1[r];
  }
  if (lane < 16) {
    pl[(size_t)(bh*KS + ks)*NTOK + qbase      + lr] = l0;
    pl[(size_t)(bh*KS + ks)*NTOK + qbase + 16 + lr] = l1;
  }
}

// ---------------------------------------------------------------------------
// Kernel 3: combine KS partials, normalize, write (B,64,H,W) output.
// ---------------------------------------------------------------------------
__global__ __launch_bounds__(256) void attn_reduce(
    const float* __restrict__ wsf, float* __restrict__ out) {
  const float* pacc = wsf + PACC_F;
  const float* pl   = wsf + PL_F;
  int blk = blockIdx.x;            // BH * 16 = 128
  int bh  = blk >> 4;
  int n   = (blk & 15)*256 + threadIdx.x;
  int b = bh >> 2, h = bh & 3;

  float lsum = 0.f;
  #pragma unroll
  for (int ks = 0; ks < KS; ++ks)
    lsum += pl[(size_t)(bh*KS + ks)*NTOK + n];
  float inv = 1.0f / lsum;

  #pragma unroll
  for (int d = 0; d < HD; ++d) {
    float s = 0.f;
    #pragma unroll
    for (int ks = 0; ks < KS; ++ks)
      s += pacc[((size_t)(bh*KS + ks)*HD + d)*NTOK + n];
    out[((size_t)(b*64 + h*HD + d))*NTOK + n] = s * inv;
  }
}

extern "C" void kernel_launch(void* const* d_in, const int* in_sizes, int n_in,
                              void* d_out, int out_size, void* d_ws, size_t ws_size,
                              hipStream_t stream) {
  const float* x    = (const float*)d_in[0];   // (2,64,64,64)
  const float* w    = (const float*)d_in[1];   // (192,64)
  const float* bias = (const float*)d_in[2];   // (192,)
  float* out  = (float*)d_out;                 // (2,64,64,64)
  ushort* wsu = (ushort*)d_ws;
  float*  wsf = (float*)d_ws;

  qkv_proj   <<<512,  192, 0, stream>>>(x, w, bias, wsu);
  attn_mfma  <<<1024, 256, 0, stream>>>(wsu, wsf);
  attn_reduce<<<128,  256, 0, stream>>>(wsf, out);
}

// Round 5
// 65.516 us; speedup vs baseline: 1.4598x; 1.4598x over previous
//
#include <hip/hip_runtime.h>

// SpatialAttention2D MFMA v5: B=2, C=64, N=4096, 4 heads x d=16, fp32 io.
// Strategy: exactly v2's verified MFMA math (S^T = mfma(K,Q); P=exp2; out^T =
// mfma(Vt,P)) and v3's verified fragment-ordered LDS layout; occupancy fixed
// by re-sharding only: 16 q/wave -> 512 blocks (2 waves/SIMD) and even/odd
// dual accumulator chains for ILP. No partials (direct output, minimal HBM).
// qkv_proj: TOK=8 -> 1024 blocks (3 waves/SIMD) for latency coverage.

#define NTOK 4096
#define HD   16
#define BH   8
#define KT   256               // keys staged per LDS tile
#define CHUNKS (KT/16)         // 16 chunks = 8 even/odd pairs per stage
#define NSTAGE (NTOK/KT)       // 16

typedef __attribute__((ext_vector_type(4))) short short4v;
typedef __attribute__((ext_vector_type(4))) float float4v;
typedef __attribute__((ext_vector_type(4))) ushort ushort4v;
typedef __attribute__((ext_vector_type(2))) unsigned uint2v;

__device__ __forceinline__ ushort f2bf(float f) {
  unsigned u = __builtin_bit_cast(unsigned, f);
  u += 0x7fffu + ((u >> 16) & 1u);          // round-to-nearest-even
  return (ushort)(u >> 16);
}

__device__ __forceinline__ float fast_exp2(float x) {
#if __has_builtin(__builtin_amdgcn_exp2f)
  return __builtin_amdgcn_exp2f(x);
#else
  return exp2f(x);
#endif
}

// ws layout in ushort elements (3 MB total)
#define QB_OFF 0
#define KB_OFF ((size_t)BH*NTOK*HD)
#define VT_OFF (2*(size_t)BH*NTOK*HD)

// ---------------------------------------------------------------------------
// Kernel 1: QKV projection (verified structure; TOK=8 for occupancy).
// q scaled by 0.25*log2(e); V written transposed.
// ---------------------------------------------------------------------------
__global__ __launch_bounds__(192) void qkv_proj(
    const float* __restrict__ x, const float* __restrict__ w,
    const float* __restrict__ bias, ushort* __restrict__ wsu) {
  const int TOK = 8;
  int blk = blockIdx.x;            // 2 * 4096/8 = 1024
  int b   = blk >> 9;
  int n0  = (blk & 511) * TOK;
  int o   = threadIdx.x;           // 0..191

  __shared__ float4 xs4[64][TOK/4];   // [64][2]
  const float4* x4 = reinterpret_cast<const float4*>(x);
  for (int idx = threadIdx.x; idx < 64*(TOK/4); idx += 192) {
    int c = idx >> 1, t4 = idx & 1;
    xs4[c][t4] = x4[((size_t)b*64 + c)*(NTOK/4) + (n0 >> 2) + t4];
  }

  float wr[64];
  const float4* w4 = reinterpret_cast<const float4*>(w + o*64);
  #pragma unroll
  for (int i = 0; i < 16; ++i) {
    float4 tt = w4[i];
    wr[4*i+0]=tt.x; wr[4*i+1]=tt.y; wr[4*i+2]=tt.z; wr[4*i+3]=tt.w;
  }
  float bb = bias[o];

  int part = o >> 6;               // 0=q,1=k,2=v
  int oo   = o & 63;
  int h    = oo >> 4;
  int dd   = oo & 15;
  int bh   = b*4 + h;
  const float QSCALE = 0.25f * 1.44269504f;

  ushort* Qb = wsu + QB_OFF;
  ushort* Kb = wsu + KB_OFF;
  ushort* Vt = wsu + VT_OFF;

  __syncthreads();

  #pragma unroll
  for (int t4 = 0; t4 < TOK/4; ++t4) {
    float a[4] = {bb, bb, bb, bb};
    #pragma unroll
    for (int c = 0; c < 64; ++c) {
      float4 xv = xs4[c][t4];
      float wv = wr[c];
      a[0] = fmaf(xv.x, wv, a[0]);
      a[1] = fmaf(xv.y, wv, a[1]);
      a[2] = fmaf(xv.z, wv, a[2]);
      a[3] = fmaf(xv.w, wv, a[3]);
    }
    if (part == 0) {
      #pragma unroll
      for (int j = 0; j < 4; ++j)
        Qb[((size_t)bh*NTOK + n0 + t4*4 + j)*HD + dd] = f2bf(a[j]*QSCALE);
    } else if (part == 1) {
      #pragma unroll
      for (int j = 0; j < 4; ++j)
        Kb[((size_t)bh*NTOK + n0 + t4*4 + j)*HD + dd] = f2bf(a[j]);
    } else {
      ushort4v vv = { f2bf(a[0]), f2bf(a[1]), f2bf(a[2]), f2bf(a[3]) };
      *(ushort4v*)(Vt + ((size_t)bh*HD + dd)*NTOK + n0 + t4*4) = vv;
    }
  }
}

// ---------------------------------------------------------------------------
// Kernel 2: MFMA flash attention. Grid = 8 bh x 64 qblk = 512 blocks,
// 4 waves x 16 q-rows (2 waves/SIMD). Direct output, no partials.
// LDS: v3-verified fragment-ordered tiles Ksw[chunk][lane] (b64 frag reads).
// Even/odd chunk pairs -> two independent MFMA/exp chains per wave.
// ---------------------------------------------------------------------------
__global__ __launch_bounds__(256, 2) void attn_mfma(
    const ushort* __restrict__ wsu, float* __restrict__ out) {
  const ushort* Qb = wsu + QB_OFF;
  const ushort* Kb = wsu + KB_OFF;
  const ushort* Vt = wsu + VT_OFF;

  int bh   = blockIdx.x >> 6;
  int qblk = blockIdx.x & 63;
  int tid  = threadIdx.x;
  int wid  = tid >> 6;
  int lane = tid & 63;
  int lr   = lane & 15;
  int g4   = (lane >> 4) << 2;
  int qbase = qblk*64 + wid*16;

  __shared__ short4v Ksw[CHUNKS][64];   // 8 KB: frag for chunk c, lane l
  __shared__ short4v Vsw[CHUNKS][64];   // 8 KB

  const ushort* Kh = Kb + (size_t)bh*NTOK*HD;
  const ushort* Vh = Vt + (size_t)bh*HD*NTOK;
  const ushort* Qh = Qb + (size_t)bh*NTOK*HD;

  // Q fragment (B operand): lane l holds Q[q=l&15][d=g4..g4+3]
  short4v qf = *(const short4v*)(Qh + (size_t)(qbase + lr)*HD + g4);

  float4v acc_e = {0.f,0.f,0.f,0.f}, acc_o = {0.f,0.f,0.f,0.f};
  float le = 0.f, lo_ = 0.f;

  // staging decomposition (v3-verified): 2 K-loads + 2 V-loads (16B) each.
  // K load i: key kk=i>>1, d-half kh=(i&1)*8; chunk kc=kk>>4,
  //   slots s0=(kh>>2)*16+(kk&15) and s0+16.
  // V load i: d row vr=i>>5, keys vc..vc+7, vc=(i&31)*8; chunk vcc=vc>>4,
  //   slots vs0=((vc&15)>>2)*16+vr and vs0+16.
  int ik0 = tid, ik1 = tid + 256;
  int kk0 = ik0 >> 1, kh0 = (ik0 & 1) * 8;
  int kk1 = ik1 >> 1, kh1 = (ik1 & 1) * 8;
  int kc0 = kk0 >> 4, ks0 = (kh0 >> 2)*16 + (kk0 & 15);
  int kc1 = kk1 >> 4, ks1 = (kh1 >> 2)*16 + (kk1 & 15);
  int vr0 = ik0 >> 5, vc0 = (ik0 & 31) * 8;
  int vr1 = ik1 >> 5, vc1 = (ik1 & 31) * 8;
  int vcc0 = vc0 >> 4, vs0 = ((vc0 & 15) >> 2)*16 + vr0;
  int vcc1 = vc1 >> 4, vs1 = ((vc1 & 15) >> 2)*16 + vr1;

  // prologue: stage 0
  uint4 pk0 = *(const uint4*)(Kh + (size_t)kk0*HD + kh0);
  uint4 pk1 = *(const uint4*)(Kh + (size_t)kk1*HD + kh1);
  uint4 pv0 = *(const uint4*)(Vh + (size_t)vr0*NTOK + vc0);
  uint4 pv1 = *(const uint4*)(Vh + (size_t)vr1*NTOK + vc1);
  {
    uint2v a = {pk0.x, pk0.y}, b2 = {pk0.z, pk0.w};
    *(uint2v*)&Ksw[kc0][ks0] = a;  *(uint2v*)&Ksw[kc0][ks0+16] = b2;
    uint2v c2 = {pk1.x, pk1.y}, d2 = {pk1.z, pk1.w};
    *(uint2v*)&Ksw[kc1][ks1] = c2; *(uint2v*)&Ksw[kc1][ks1+16] = d2;
    uint2v e2 = {pv0.x, pv0.y}, f2 = {pv0.z, pv0.w};
    *(uint2v*)&Vsw[vcc0][vs0] = e2; *(uint2v*)&Vsw[vcc0][vs0+16] = f2;
    uint2v g2 = {pv1.x, pv1.y}, h2 = {pv1.z, pv1.w};
    *(uint2v*)&Vsw[vcc1][vs1] = g2; *(uint2v*)&Vsw[vcc1][vs1+16] = h2;
  }
  __syncthreads();

  for (int s = 0; s < NSTAGE; ++s) {
    if (s + 1 < NSTAGE) {          // T14: issue next-stage loads early
      int k0n = (s + 1) * KT;
      pk0 = *(const uint4*)(Kh + (size_t)(k0n + kk0)*HD + kh0);
      pk1 = *(const uint4*)(Kh + (size_t)(k0n + kk1)*HD + kh1);
      pv0 = *(const uint4*)(Vh + (size_t)vr0*NTOK + k0n + vc0);
      pv1 = *(const uint4*)(Vh + (size_t)vr1*NTOK + k0n + vc1);
    }
    #pragma unroll
    for (int p = 0; p < CHUNKS/2; ++p) {
      short4v kf_e = Ksw[2*p  ][lane];   // K[key=32p   +lr][d=g4..g4+3]
      short4v kf_o = Ksw[2*p+1][lane];   // K[key=32p+16+lr][d=g4..g4+3]
      short4v vf_e = Vsw[2*p  ][lane];   // V^T[d=lr][key=32p   +g4..+3]
      short4v vf_o = Vsw[2*p+1][lane];   // V^T[d=lr][key=32p+16+g4..+3]
      float4v zero = {0.f,0.f,0.f,0.f};
      float4v se = __builtin_amdgcn_mfma_f32_16x16x16bf16_1k(kf_e, qf, zero, 0, 0, 0);
      float4v so = __builtin_amdgcn_mfma_f32_16x16x16bf16_1k(kf_o, qf, zero, 0, 0, 0);
      short4v pbe, pbo;
      #pragma unroll
      for (int r = 0; r < 4; ++r) {
        float pe = fast_exp2(se[r]); le  += pe; pbe[r] = (short)f2bf(pe);
        float po = fast_exp2(so[r]); lo_ += po; pbo[r] = (short)f2bf(po);
      }
      acc_e = __builtin_amdgcn_mfma_f32_16x16x16bf16_1k(vf_e, pbe, acc_e, 0, 0, 0);
      acc_o = __builtin_amdgcn_mfma_f32_16x16x16bf16_1k(vf_o, pbo, acc_o, 0, 0, 0);
    }
    __syncthreads();
    if (s + 1 < NSTAGE) {
      uint2v a = {pk0.x, pk0.y}, b2 = {pk0.z, pk0.w};
      *(uint2v*)&Ksw[kc0][ks0] = a;  *(uint2v*)&Ksw[kc0][ks0+16] = b2;
      uint2v c2 = {pk1.x, pk1.y}, d2 = {pk1.z, pk1.w};
      *(uint2v*)&Ksw[kc1][ks1] = c2; *(uint2v*)&Ksw[kc1][ks1+16] = d2;
      uint2v e2 = {pv0.x, pv0.y}, f2 = {pv0.z, pv0.w};
      *(uint2v*)&Vsw[vcc0][vs0] = e2; *(uint2v*)&Vsw[vcc0][vs0+16] = f2;
      uint2v g2 = {pv1.x, pv1.y}, h2 = {pv1.z, pv1.w};
      *(uint2v*)&Vsw[vcc1][vs1] = g2; *(uint2v*)&Vsw[vcc1][vs1+16] = h2;
      __syncthreads();
    }
  }

  // total l per q: sum the 4 lane-groups (lanes l^16, l^32 hold same q)
  float l = le + lo_;
  l += __shfl_xor(l, 16); l += __shfl_xor(l, 32);
  float inv = 1.0f / l;

  // acc^T: lane l reg r = out[q=l&15][d=g4+r]; out is channel-major
  int b = bh >> 2, h = bh & 3;
  float* ob = out + ((size_t)(b*64 + h*16 + g4)) * NTOK;
  #pragma unroll
  for (int r = 0; r < 4; ++r)
    ob[(size_t)r*NTOK + qbase + lr] = (acc_e[r] + acc_o[r]) * inv;
}

extern "C" void kernel_launch(void* const* d_in, const int* in_sizes, int n_in,
                              void* d_out, int out_size, void* d_ws, size_t ws_size,
                              hipStream_t stream) {
  const float* x    = (const float*)d_in[0];   // (2,64,64,64)
  const float* w    = (const float*)d_in[1];   // (192,64)
  const float* bias = (const float*)d_in[2];   // (192,)
  float* out  = (float*)d_out;                 // (2,64,64,64)
  ushort* wsu = (ushort*)d_ws;                 // 3 MB used

  qkv_proj <<<1024, 192, 0, stream>>>(x, w, bias, wsu);
  attn_mfma<<<512,  256, 0, stream>>>(wsu, out);
}